// Round 1
// baseline (1048.005 us; speedup 1.0000x reference)
//
#include <hip/hip_runtime.h>
#include <stdint.h>

#define B_    64
#define T_    49
#define E_    512
#define H_    512
#define ENC_  1024
#define V_    32000
#define G4_   2048        // 4*H
#define M_    3136        // T_*B_
#define MPAD_ 3200        // padded to 25*128

typedef __attribute__((ext_vector_type(8))) short bf16x8;
typedef __attribute__((ext_vector_type(4))) float f32x4;

static __device__ __forceinline__ unsigned short f2bf(float f) {
  union { float f; uint32_t u; } v; v.f = f;
  uint32_t r = v.u + 0x7FFFu + ((v.u >> 16) & 1u);
  return (unsigned short)(r >> 16);
}

static __device__ __forceinline__ void async16(const void* g, void* lds) {
  __builtin_amdgcn_global_load_lds(
      (const __attribute__((address_space(1))) unsigned int*)g,
      (__attribute__((address_space(3))) unsigned int*)lds, 16, 0, 0);
}

static __device__ __forceinline__ float sigf(float x) { return 1.0f / (1.0f + expf(-x)); }

// ---------------- convert weights to bf16 (+ embeddings transpose (b,t)->(t,b)) ----------------
__global__ __launch_bounds__(256) void convert_kernel(
    const float* __restrict__ Wih, const float* __restrict__ Whh,
    const float* __restrict__ Wfc, const float* __restrict__ emb,
    unsigned short* __restrict__ WihB, unsigned short* __restrict__ WhhB,
    unsigned short* __restrict__ WfcB, unsigned short* __restrict__ AxB) {
  const int n_wih = (G4_ * E_) / 4;        // 262144
  const int n_whh = (G4_ * H_) / 4;        // 262144
  const int n_wfc = (V_ * H_) / 4;         // 4096000
  const int n_emb = (B_ * T_ * E_) / 4;    // 401408
  const int n_pad = ((MPAD_ - M_) * E_) / 4; // 8192
  const long total = (long)n_wih + n_whh + n_wfc + n_emb + n_pad;
  for (long u = (long)blockIdx.x * blockDim.x + threadIdx.x; u < total;
       u += (long)gridDim.x * blockDim.x) {
    long i = u;
    if (i < n_wih) {
      float4 v = ((const float4*)Wih)[i];
      ushort4 o; o.x = f2bf(v.x); o.y = f2bf(v.y); o.z = f2bf(v.z); o.w = f2bf(v.w);
      ((ushort4*)WihB)[i] = o; continue;
    }
    i -= n_wih;
    if (i < n_whh) {
      float4 v = ((const float4*)Whh)[i];
      ushort4 o; o.x = f2bf(v.x); o.y = f2bf(v.y); o.z = f2bf(v.z); o.w = f2bf(v.w);
      ((ushort4*)WhhB)[i] = o; continue;
    }
    i -= n_whh;
    if (i < n_wfc) {
      float4 v = ((const float4*)Wfc)[i];
      ushort4 o; o.x = f2bf(v.x); o.y = f2bf(v.y); o.z = f2bf(v.z); o.w = f2bf(v.w);
      ((ushort4*)WfcB)[i] = o; continue;
    }
    i -= n_wfc;
    if (i < n_emb) {
      // src element (b,t,e4) -> dst row t*64+b
      int bt = (int)(i >> 7);            // E_/4 = 128
      int e4 = (int)(i & 127);
      int b = bt / T_, t = bt - b * T_;
      float4 v = ((const float4*)emb)[i];
      ushort4 o; o.x = f2bf(v.x); o.y = f2bf(v.y); o.z = f2bf(v.z); o.w = f2bf(v.w);
      ((ushort4*)AxB)[((long)(t * 64 + b) << 7) + e4] = o; continue;
    }
    i -= n_emb;
    // zero pad rows M_..MPAD_-1 of AxB
    ushort4 z; z.x = z.y = z.z = z.w = 0;
    ((ushort4*)AxB)[((long)M_ << 7) + i] = z;
  }
}

// ---------------- init: h0, c0 (fp32) + decode_lengths to out tail ----------------
__global__ __launch_bounds__(256) void init_kernel(
    const float* __restrict__ enc, const int* __restrict__ cap,
    const float* __restrict__ Wh, const float* __restrict__ bh,
    const float* __restrict__ Wc, const float* __restrict__ bc,
    unsigned short* __restrict__ h0b, float* __restrict__ c0,
    float* __restrict__ out_dl) {
  __shared__ __align__(16) float e[ENC_];
  const int b = blockIdx.x, q = blockIdx.y, tid = threadIdx.x;
  ((float4*)e)[tid] = ((const float4*)(enc + (size_t)b * ENC_))[tid];
  __syncthreads();
  const bool is_c = tid >= 128;
  const int j = q * 128 + (tid & 127);
  const float* W = is_c ? Wc : Wh;
  float s = is_c ? bc[j] : bh[j];
  const float4* wr = (const float4*)(W + (size_t)j * ENC_);
  const float4* e4 = (const float4*)e;
#pragma unroll 4
  for (int k = 0; k < ENC_ / 4; ++k) {
    float4 w = wr[k], v = e4[k];
    s += w.x * v.x + w.y * v.y + w.z * v.z + w.w * v.w;
  }
  if (is_c) c0[(size_t)b * H_ + j] = s;
  else      h0b[(size_t)b * H_ + j] = f2bf(s);
  if (b == 0 && q == 0 && tid < B_) out_dl[tid] = (float)(cap[tid] - 1);
}

// ---------------- tiled bf16 GEMM, 128x128 tile, K=512, m97-style ----------------
// C[row][col] = sum_k A[row][k] * Bm[col][k]   (A: Mx512 bf16, Bm: Nx512 bf16 row-major)
// P3=false: C fp32 [.,N] + bias0[col]+bias1[col]
// P3=true : scatter to out[(b*T_+t)*V_+col], masked by t < cap[b]-1, + bias0[col]
template <bool P3>
__global__ __launch_bounds__(256) void gemm_bf16(
    const unsigned short* __restrict__ A, const unsigned short* __restrict__ Bm,
    float* __restrict__ C, const float* __restrict__ bias0, const float* __restrict__ bias1,
    const int* __restrict__ cap, int N, float* __restrict__ outp) {
  __shared__ __align__(16) unsigned short As[2][128 * 64];
  __shared__ __align__(16) unsigned short Bs[2][128 * 64];
  const int tid = threadIdx.x, lane = tid & 63, wid = tid >> 6;
  const int nt = blockIdx.x, mt = blockIdx.y;
  const int wr = wid >> 1, wc = wid & 1;
  const int m0 = mt * 128, n0 = nt * 128;
  f32x4 acc[4][4] = {};

  auto stage = [&](int buf, int kit) {
    const int k0b = kit * 128;  // byte offset along K
#pragma unroll
    for (int i = 0; i < 4; ++i) {
      int chunk = wid * 4 + i;          // 0..15, 1KB each
      int d = chunk * 1024 + lane * 16; // dest byte in tile
      int row = d >> 7, colb = d & 127;
      int sc = colb ^ ((row & 7) << 4); // pre-swizzled source (T2 both-sides)
      async16((const char*)A + (size_t)(m0 + row) * 1024 + k0b + sc,
              (char*)&As[buf][0] + chunk * 1024);
      async16((const char*)Bm + (size_t)(n0 + row) * 1024 + k0b + sc,
              (char*)&Bs[buf][0] + chunk * 1024);
    }
  };

  stage(0, 0);
  __syncthreads();
  for (int kit = 0; kit < 8; ++kit) {
    const int buf = kit & 1;
    if (kit < 7) stage(buf ^ 1, kit + 1);
    const char* Ab = (const char*)&As[buf][0];
    const char* Bb = (const char*)&Bs[buf][0];
#pragma unroll
    for (int kb = 0; kb < 2; ++kb) {
      const int colb = kb * 64 + (lane >> 4) * 16;
      bf16x8 af[4], bfb[4];
#pragma unroll
      for (int rt = 0; rt < 4; ++rt) {
        int ar = wr * 64 + rt * 16 + (lane & 15);
        af[rt] = *(const bf16x8*)(Ab + ar * 128 + (colb ^ ((ar & 7) << 4)));
        int br = wc * 64 + rt * 16 + (lane & 15);
        bfb[rt] = *(const bf16x8*)(Bb + br * 128 + (colb ^ ((br & 7) << 4)));
      }
#pragma unroll
      for (int i = 0; i < 4; ++i)
#pragma unroll
        for (int j = 0; j < 4; ++j)
          acc[i][j] = __builtin_amdgcn_mfma_f32_16x16x32_bf16(af[i], bfb[j], acc[i][j], 0, 0, 0);
    }
    __syncthreads();
  }
  // epilogue: D lane layout col=lane&15, row=(lane>>4)*4+r
#pragma unroll
  for (int i = 0; i < 4; ++i) {
    const int rbase = m0 + wr * 64 + i * 16 + (lane >> 4) * 4;
#pragma unroll
    for (int j = 0; j < 4; ++j) {
      const int col = n0 + wc * 64 + j * 16 + (lane & 15);
#pragma unroll
      for (int r = 0; r < 4; ++r) {
        const int row = rbase + r;
        if constexpr (!P3) {
          C[(size_t)row * N + col] = acc[i][j][r] + bias0[col] + bias1[col];
        } else {
          if (row < M_) {
            const int t = row >> 6, b = row & 63;
            const float v = (t < cap[b] - 1) ? (acc[i][j][r] + bias0[col]) : 0.0f;
            outp[((size_t)b * T_ + t) * V_ + col] = v;
          }
        }
      }
    }
  }
}

// ---------------- one LSTM step: gates = Gx[t] + h @ Whh^T ; elementwise ----------------
// 32 WGs; WG w owns h-cols [w*16, w*16+16); wave g computes gate group g (i,f,g,o)
__global__ __launch_bounds__(256) void lstm_step(
    const float* __restrict__ Gx, const unsigned short* __restrict__ Whh,
    const unsigned short* __restrict__ h_in, unsigned short* __restrict__ h_out,
    float* __restrict__ c_st, unsigned short* __restrict__ Hall,
    const int* __restrict__ cap, int t) {
  __shared__ __align__(16) float gl[4][64][16];
  const int tid = threadIdx.x, lane = tid & 63, g = tid >> 6;
  const int w = blockIdx.x;
  const int hc0 = w * 16;
  const int gc = g * 512 + hc0 + (lane & 15);  // gate column (B operand row)
  const int ko = (lane >> 4) * 8;
  f32x4 acc[4] = {};
#pragma unroll
  for (int kb = 0; kb < 16; ++kb) {
    bf16x8 bf = *(const bf16x8*)&Whh[(size_t)gc * 512 + kb * 32 + ko];
#pragma unroll
    for (int rt = 0; rt < 4; ++rt) {
      bf16x8 af = *(const bf16x8*)&h_in[(size_t)(rt * 16 + (lane & 15)) * 512 + kb * 32 + ko];
      acc[rt] = __builtin_amdgcn_mfma_f32_16x16x32_bf16(af, bf, acc[rt], 0, 0, 0);
    }
  }
#pragma unroll
  for (int rt = 0; rt < 4; ++rt)
#pragma unroll
    for (int r = 0; r < 4; ++r)
      gl[g][rt * 16 + (lane >> 4) * 4 + r][lane & 15] = acc[rt][r];
  __syncthreads();

  const int b = tid >> 2, hq = (tid & 3) * 4;
  const size_t gxr = ((size_t)t * 64 + b) * (size_t)G4_ + hc0 + hq;
  f32x4 vi = *(const f32x4*)&Gx[gxr + 0]   + *(const f32x4*)&gl[0][b][hq];
  f32x4 vf = *(const f32x4*)&Gx[gxr + 512] + *(const f32x4*)&gl[1][b][hq];
  f32x4 vg = *(const f32x4*)&Gx[gxr + 1024]+ *(const f32x4*)&gl[2][b][hq];
  f32x4 vo = *(const f32x4*)&Gx[gxr + 1536]+ *(const f32x4*)&gl[3][b][hq];
  f32x4 cold = *(const f32x4*)&c_st[(size_t)b * H_ + hc0 + hq];
  f32x4 cn, hn;
#pragma unroll
  for (int k = 0; k < 4; ++k) {
    float iv = sigf(vi[k]), fv = sigf(vf[k]), gv = tanhf(vg[k]), ov = sigf(vo[k]);
    cn[k] = fv * cold[k] + iv * gv;
    hn[k] = ov * tanhf(cn[k]);
  }
  const bool m = t < cap[b] - 1;
  ushort4 hb; hb.x = f2bf(hn[0]); hb.y = f2bf(hn[1]); hb.z = f2bf(hn[2]); hb.w = f2bf(hn[3]);
  *(ushort4*)&Hall[((size_t)t * 64 + b) * H_ + hc0 + hq] = hb;  // pre-mask h_new (preds input)
  ushort4 hold = *(const ushort4*)&h_in[(size_t)b * H_ + hc0 + hq];
  *(ushort4*)&h_out[(size_t)b * H_ + hc0 + hq] = m ? hb : hold;
  if (m) *(f32x4*)&c_st[(size_t)b * H_ + hc0 + hq] = cn;
}

// ---------------- launch ----------------
extern "C" void kernel_launch(void* const* d_in, const int* in_sizes, int n_in,
                              void* d_out, int out_size, void* d_ws, size_t ws_size,
                              hipStream_t stream) {
  const float* emb = (const float*)d_in[0];
  const float* enc = (const float*)d_in[1];
  const int*   cap = (const int*)d_in[2];
  const float* Wih = (const float*)d_in[3];
  const float* Whh = (const float*)d_in[4];
  const float* bih = (const float*)d_in[5];
  const float* bhh = (const float*)d_in[6];
  const float* Wh0 = (const float*)d_in[7];
  const float* bh0 = (const float*)d_in[8];
  const float* Wc0 = (const float*)d_in[9];
  const float* bc0 = (const float*)d_in[10];
  const float* Wfc = (const float*)d_in[11];
  const float* bfc = (const float*)d_in[12];
  float* out = (float*)d_out;

  char* ws = (char*)d_ws;
  size_t o = 0;
  auto carve = [&](size_t bytes) { void* p = ws + o; o += (bytes + 255) & ~(size_t)255; return p; };
  unsigned short* WihB = (unsigned short*)carve((size_t)G4_ * E_ * 2);   // 2 MB
  unsigned short* WhhB = (unsigned short*)carve((size_t)G4_ * H_ * 2);   // 2 MB
  unsigned short* WfcB = (unsigned short*)carve((size_t)V_ * H_ * 2);    // 32.8 MB
  unsigned short* AxB  = (unsigned short*)carve((size_t)MPAD_ * E_ * 2); // 3.3 MB
  float*          Gx   = (float*)carve((size_t)MPAD_ * G4_ * 4);         // 26.2 MB
  unsigned short* Hall = (unsigned short*)carve((size_t)MPAD_ * H_ * 2); // 3.3 MB
  unsigned short* hb0  = (unsigned short*)carve((size_t)B_ * H_ * 2);
  unsigned short* hb1  = (unsigned short*)carve((size_t)B_ * H_ * 2);
  float*          cst  = (float*)carve((size_t)B_ * H_ * 4);
  (void)ws_size; (void)in_sizes; (void)n_in; (void)out_size;

  convert_kernel<<<dim3(2048), dim3(256), 0, stream>>>(Wih, Whh, Wfc, emb, WihB, WhhB, WfcB, AxB);
  init_kernel<<<dim3(64, 4), dim3(256), 0, stream>>>(enc, cap, Wh0, bh0, Wc0, bc0, hb0, cst,
                                                     out + (size_t)B_ * T_ * V_);
  gemm_bf16<false><<<dim3(G4_ / 128, MPAD_ / 128), dim3(256), 0, stream>>>(
      AxB, WihB, Gx, bih, bhh, nullptr, G4_, nullptr);
  unsigned short* hbufs[2] = {hb0, hb1};
  for (int t = 0; t < T_; ++t) {
    lstm_step<<<dim3(32), dim3(256), 0, stream>>>(Gx, WhhB, hbufs[t & 1], hbufs[(t + 1) & 1],
                                                  cst, Hall, cap, t);
  }
  gemm_bf16<true><<<dim3(V_ / 128, MPAD_ / 128), dim3(256), 0, stream>>>(
      Hall, WfcB, nullptr, bfc, nullptr, cap, V_, out);
}

// Round 2
// 693.459 us; speedup vs baseline: 1.5113x; 1.5113x over previous
//
#include <hip/hip_runtime.h>
#include <stdint.h>

#define B_    64
#define T_    49
#define E_    512
#define H_    512
#define ENC_  1024
#define V_    32000
#define G4_   2048        // 4*H
#define M_    3136        // T_*B_
#define MPAD_ 3200        // padded to 25*128
#define NWG_REC 32

typedef __attribute__((ext_vector_type(8))) short bf16x8;
typedef __attribute__((ext_vector_type(4))) float f32x4;

static __device__ __forceinline__ unsigned short f2bf(float f) {
  union { float f; uint32_t u; } v; v.f = f;
  uint32_t r = v.u + 0x7FFFu + ((v.u >> 16) & 1u);
  return (unsigned short)(r >> 16);
}

static __device__ __forceinline__ void async16(const void* g, void* lds) {
  __builtin_amdgcn_global_load_lds(
      (const __attribute__((address_space(1))) unsigned int*)g,
      (__attribute__((address_space(3))) unsigned int*)lds, 16, 0, 0);
}

static __device__ __forceinline__ float sigf(float x) { return 1.0f / (1.0f + expf(-x)); }

// ---------------- convert weights to bf16 (+ embeddings transpose (b,t)->(t,b)) ----------------
__global__ __launch_bounds__(256) void convert_kernel(
    const float* __restrict__ Wih, const float* __restrict__ Whh,
    const float* __restrict__ Wfc, const float* __restrict__ emb,
    unsigned short* __restrict__ WihB, unsigned short* __restrict__ WhhB,
    unsigned short* __restrict__ WfcB, unsigned short* __restrict__ AxB) {
  const int n_wih = (G4_ * E_) / 4;        // 262144
  const int n_whh = (G4_ * H_) / 4;        // 262144
  const int n_wfc = (V_ * H_) / 4;         // 4096000
  const int n_emb = (B_ * T_ * E_) / 4;    // 401408
  const int n_pad = ((MPAD_ - M_) * E_) / 4; // 8192
  const long total = (long)n_wih + n_whh + n_wfc + n_emb + n_pad;
  for (long u = (long)blockIdx.x * blockDim.x + threadIdx.x; u < total;
       u += (long)gridDim.x * blockDim.x) {
    long i = u;
    if (i < n_wih) {
      float4 v = ((const float4*)Wih)[i];
      ushort4 o; o.x = f2bf(v.x); o.y = f2bf(v.y); o.z = f2bf(v.z); o.w = f2bf(v.w);
      ((ushort4*)WihB)[i] = o; continue;
    }
    i -= n_wih;
    if (i < n_whh) {
      float4 v = ((const float4*)Whh)[i];
      ushort4 o; o.x = f2bf(v.x); o.y = f2bf(v.y); o.z = f2bf(v.z); o.w = f2bf(v.w);
      ((ushort4*)WhhB)[i] = o; continue;
    }
    i -= n_whh;
    if (i < n_wfc) {
      float4 v = ((const float4*)Wfc)[i];
      ushort4 o; o.x = f2bf(v.x); o.y = f2bf(v.y); o.z = f2bf(v.z); o.w = f2bf(v.w);
      ((ushort4*)WfcB)[i] = o; continue;
    }
    i -= n_wfc;
    if (i < n_emb) {
      int bt = (int)(i >> 7);            // E_/4 = 128
      int e4 = (int)(i & 127);
      int b = bt / T_, t = bt - b * T_;
      float4 v = ((const float4*)emb)[i];
      ushort4 o; o.x = f2bf(v.x); o.y = f2bf(v.y); o.z = f2bf(v.z); o.w = f2bf(v.w);
      ((ushort4*)AxB)[((long)(t * 64 + b) << 7) + e4] = o; continue;
    }
    i -= n_emb;
    ushort4 z; z.x = z.y = z.z = z.w = 0;
    ((ushort4*)AxB)[((long)M_ << 7) + i] = z;
  }
}

// ---------------- init: h0, c0 (fp32) + decode_lengths to out tail ----------------
__global__ __launch_bounds__(256) void init_kernel(
    const float* __restrict__ enc, const int* __restrict__ cap,
    const float* __restrict__ Wh, const float* __restrict__ bh,
    const float* __restrict__ Wc, const float* __restrict__ bc,
    unsigned short* __restrict__ h0b, float* __restrict__ c0,
    float* __restrict__ out_dl) {
  __shared__ __align__(16) float e[ENC_];
  const int b = blockIdx.x, q = blockIdx.y, tid = threadIdx.x;
  ((float4*)e)[tid] = ((const float4*)(enc + (size_t)b * ENC_))[tid];
  __syncthreads();
  const bool is_c = tid >= 128;
  const int j = q * 128 + (tid & 127);
  const float* W = is_c ? Wc : Wh;
  float s = is_c ? bc[j] : bh[j];
  const float4* wr = (const float4*)(W + (size_t)j * ENC_);
  const float4* e4 = (const float4*)e;
#pragma unroll 4
  for (int k = 0; k < ENC_ / 4; ++k) {
    float4 w = wr[k], v = e4[k];
    s += w.x * v.x + w.y * v.y + w.z * v.z + w.w * v.w;
  }
  if (is_c) c0[(size_t)b * H_ + j] = s;
  else      h0b[(size_t)b * H_ + j] = f2bf(s);
  if (b == 0 && q == 0 && tid < B_) out_dl[tid] = (float)(cap[tid] - 1);
}

// ---------------- tiled bf16 GEMM, 128x128 tile, K=512 ----------------
// C[row][col] = sum_k A[row][k] * Bm[col][k]
// P3=false: 2D grid (nt,mt); C fp32 [.,N] + bias0[col]+bias1[col]
// P3=true : 1D grid 6250 XCD-swizzled, mt-fastest; LDS-transposed coalesced
//           masked store to out[(b*T_+t)*V_+col] + bias0[col]
template <bool P3>
__global__ __launch_bounds__(256) void gemm_bf16(
    const unsigned short* __restrict__ A, const unsigned short* __restrict__ Bm,
    float* __restrict__ C, const float* __restrict__ bias0, const float* __restrict__ bias1,
    const int* __restrict__ cap, int N, float* __restrict__ outp) {
  __shared__ __align__(16) char smem[65536];   // As[2]|Bs[2] during loop; Ct after
  const int tid = threadIdx.x, lane = tid & 63, wid = tid >> 6;
  int mt, nt;
  if constexpr (P3) {
    const int bid = blockIdx.x;           // 6250 = 25*250; q=781 r=2
    const int xcd = bid & 7, idx = bid >> 3;
    const int wgid = (xcd < 2 ? xcd * 782 : 1564 + (xcd - 2) * 781) + idx;
    mt = wgid % 25; nt = wgid / 25;
  } else {
    nt = blockIdx.x; mt = blockIdx.y;
  }
  const int wr = wid >> 1, wc = wid & 1;
  const int m0 = mt * 128, n0 = nt * 128;
  f32x4 acc[4][4] = {};

  auto stage = [&](int buf, int kit) {
    const int k0b = kit * 128;  // byte offset along K
    char* Abase = smem + buf * 16384;
    char* Bbase = smem + 32768 + buf * 16384;
#pragma unroll
    for (int i = 0; i < 4; ++i) {
      int chunk = wid * 4 + i;          // 0..15, 1KB each
      int d = chunk * 1024 + lane * 16; // per-lane dest byte in tile
      int row = d >> 7, colb = d & 127;
      int sc = colb ^ ((row & 7) << 4); // pre-swizzled source (T2 both-sides)
      async16((const char*)A + (size_t)(m0 + row) * 1024 + k0b + sc, Abase + chunk * 1024);
      async16((const char*)Bm + (size_t)(n0 + row) * 1024 + k0b + sc, Bbase + chunk * 1024);
    }
  };

  stage(0, 0);
  __syncthreads();
  for (int kit = 0; kit < 8; ++kit) {
    const int buf = kit & 1;
    if (kit < 7) stage(buf ^ 1, kit + 1);
    const char* Ab = smem + buf * 16384;
    const char* Bb = smem + 32768 + buf * 16384;
#pragma unroll
    for (int kb = 0; kb < 2; ++kb) {
      const int colb = kb * 64 + (lane >> 4) * 16;
      bf16x8 af[4], bfb[4];
#pragma unroll
      for (int rt = 0; rt < 4; ++rt) {
        int ar = wr * 64 + rt * 16 + (lane & 15);
        af[rt] = *(const bf16x8*)(Ab + ar * 128 + (colb ^ ((ar & 7) << 4)));
        int br = wc * 64 + rt * 16 + (lane & 15);
        bfb[rt] = *(const bf16x8*)(Bb + br * 128 + (colb ^ ((br & 7) << 4)));
      }
#pragma unroll
      for (int i = 0; i < 4; ++i)
#pragma unroll
        for (int j = 0; j < 4; ++j)
          acc[i][j] = __builtin_amdgcn_mfma_f32_16x16x32_bf16(af[i], bfb[j], acc[i][j], 0, 0, 0);
    }
    __syncthreads();
  }
  // D lane layout: col=lane&15, row=(lane>>4)*4+r
  if constexpr (!P3) {
#pragma unroll
    for (int i = 0; i < 4; ++i) {
      const int rbase = m0 + wr * 64 + i * 16 + (lane >> 4) * 4;
#pragma unroll
      for (int j = 0; j < 4; ++j) {
        const int col = n0 + wc * 64 + j * 16 + (lane & 15);
#pragma unroll
        for (int r = 0; r < 4; ++r)
          C[(size_t)(rbase + r) * N + col] = acc[i][j][r] + bias0[col] + bias1[col];
      }
    }
  } else {
    // transpose through LDS (XOR-swizzled), then coalesced float4 row stores
    float* Ct = (float*)smem;   // [128][128] f32, chunk-swizzled by row&7
#pragma unroll
    for (int j = 0; j < 4; ++j) {
      const int colL = wc * 64 + j * 16 + (lane & 15);
      const float bz = bias0[n0 + colL];
#pragma unroll
      for (int i = 0; i < 4; ++i) {
        const int rb = wr * 64 + i * 16 + (lane >> 4) * 4;
#pragma unroll
        for (int r = 0; r < 4; ++r) {
          const int row = rb + r;
          Ct[row * 128 + (colL ^ ((row & 7) << 2))] = acc[i][j][r] + bz;
        }
      }
    }
    __syncthreads();
    const int c4 = tid & 31;          // 16B chunk within row
    const int rsub = tid >> 5;        // 0..7
#pragma unroll
    for (int itr = 0; itr < 16; ++itr) {
      const int row = itr * 8 + rsub;
      const int grow = m0 + row;
      if (grow >= M_) continue;
      const int tt = grow >> 6, bb = grow & 63;
      f32x4 v = {0.0f, 0.0f, 0.0f, 0.0f};
      if (tt < cap[bb] - 1)
        v = *(const f32x4*)&Ct[row * 128 + ((c4 ^ (row & 7)) << 2)];
      *(f32x4*)(outp + ((size_t)bb * T_ + tt) * V_ + n0 + (c4 << 2)) = v;
    }
  }
}

// ---------------- persistent LSTM recurrence: all 49 steps in one kernel ----------------
// 32 WGs x 256 thr. WG w owns h-cols [16w,16w+16) i.e. gate-cols {g*512+16w..+16}.
// Whh panel (64KB) preloaded to LDS once; h staged to LDS each step; c + masked-h
// carried in registers; software grid barrier between steps (double-buffered h).
__global__ __launch_bounds__(256) void lstm_persist(
    const float* __restrict__ Gx, const unsigned short* __restrict__ WhhB,
    unsigned short* __restrict__ hb0, unsigned short* __restrict__ hb1,
    const float* __restrict__ c0, unsigned short* __restrict__ Hall,
    const int* __restrict__ cap, int* __restrict__ bar) {
  __shared__ __align__(16) unsigned short Wl[64 * 512];   // 64KB, XOR-swizzled rows
  __shared__ __align__(16) unsigned short Hs[64 * 512];   // 64KB, XOR-swizzled rows
  __shared__ __align__(16) float gl[4][64][16];           // 16KB
  const int tid = threadIdx.x, lane = tid & 63, g = tid >> 6;
  const int w = blockIdx.x, hc0 = w * 16;

  // ---- preload Whh gate-col panel into Wl (row r = g*16+c -> global row g*512+hc0+c)
  {
    const int destb = tid * 16;
#pragma unroll
    for (int it = 0; it < 16; ++it) {
      int d = it * 4096 + destb;
      int rrow = d >> 10, inrow = d & 1023;
      int gc = (rrow >> 4) * 512 + hc0 + (rrow & 15);
      async16((const char*)WhhB + (size_t)gc * 1024 + (inrow ^ ((rrow & 7) << 4)),
              (char*)Wl + it * 4096 + g * 1024);
    }
  }
  // ---- per-thread persistent state
  const int b = tid >> 2, hq = (tid & 3) * 4, hc = hc0 + hq;
  const int dl = cap[b] - 1;
  f32x4 creg = *(const f32x4*)&c0[(size_t)b * H_ + hc];
  ushort4 hold = *(const ushort4*)&hb0[(size_t)b * H_ + hc];
  unsigned short* hbuf[2] = {hb0, hb1};
  __syncthreads();  // drains Wl loads too

  for (int t = 0; t < T_; ++t) {
    // stage h(t) into Hs
    const unsigned short* hin = hbuf[t & 1];
    {
      const int destb = tid * 16;
#pragma unroll
      for (int it = 0; it < 16; ++it) {
        int d = it * 4096 + destb;
        int rrow = d >> 10, inrow = d & 1023;
        async16((const char*)hin + (size_t)rrow * 1024 + (inrow ^ ((rrow & 7) << 4)),
                (char*)Hs + it * 4096 + g * 1024);
      }
    }
    __syncthreads();
    // wave g: gates block = h(t) @ Whh[g-cols]^T
    f32x4 acc[4] = {};
#pragma unroll
    for (int kb = 0; kb < 16; ++kb) {
      const int kbyte = kb * 64 + (lane >> 4) * 16;
      const int br = g * 16 + (lane & 15);
      bf16x8 bfr = *(const bf16x8*)((const char*)Wl + br * 1024 + (kbyte ^ ((br & 7) << 4)));
#pragma unroll
      for (int rt = 0; rt < 4; ++rt) {
        const int ar = rt * 16 + (lane & 15);
        bf16x8 afr = *(const bf16x8*)((const char*)Hs + ar * 1024 + (kbyte ^ ((ar & 7) << 4)));
        acc[rt] = __builtin_amdgcn_mfma_f32_16x16x32_bf16(afr, bfr, acc[rt], 0, 0, 0);
      }
    }
#pragma unroll
    for (int rt = 0; rt < 4; ++rt)
#pragma unroll
      for (int r = 0; r < 4; ++r)
        gl[g][rt * 16 + (lane >> 4) * 4 + r][lane & 15] = acc[rt][r];
    __syncthreads();
    // elementwise: thread owns (batch b, h-cols hc..hc+4)
    const size_t gxr = ((size_t)t * 64 + b) * (size_t)G4_ + hc;
    f32x4 vi = *(const f32x4*)&Gx[gxr + 0]    + *(const f32x4*)&gl[0][b][hq];
    f32x4 vf = *(const f32x4*)&Gx[gxr + 512]  + *(const f32x4*)&gl[1][b][hq];
    f32x4 vg = *(const f32x4*)&Gx[gxr + 1024] + *(const f32x4*)&gl[2][b][hq];
    f32x4 vo = *(const f32x4*)&Gx[gxr + 1536] + *(const f32x4*)&gl[3][b][hq];
    f32x4 cn;
    ushort4 hb16;
    {
      float hv[4];
#pragma unroll
      for (int k = 0; k < 4; ++k) {
        float iv = sigf(vi[k]), fv = sigf(vf[k]), gv = tanhf(vg[k]), ov = sigf(vo[k]);
        cn[k] = fv * creg[k] + iv * gv;
        hv[k] = ov * tanhf(cn[k]);
      }
      hb16.x = f2bf(hv[0]); hb16.y = f2bf(hv[1]); hb16.z = f2bf(hv[2]); hb16.w = f2bf(hv[3]);
    }
    *(ushort4*)&Hall[((size_t)t * 64 + b) * H_ + hc] = hb16;  // pre-mask h_new
    if (t < dl) { hold = hb16; creg = cn; }
    *(ushort4*)&hbuf[(t + 1) & 1][(size_t)b * H_ + hc] = hold;
    // grid barrier (monotonic counter; bar zeroed per call by hipMemsetAsync)
    if (t + 1 < T_) {
      __syncthreads();
      if (tid == 0) {
        __threadfence();
        __hip_atomic_fetch_add(bar, 1, __ATOMIC_RELEASE, __HIP_MEMORY_SCOPE_AGENT);
        while (__hip_atomic_load(bar, __ATOMIC_ACQUIRE, __HIP_MEMORY_SCOPE_AGENT) <
               NWG_REC * (t + 1)) {
          __builtin_amdgcn_s_sleep(2);
        }
        __threadfence();
      }
      __syncthreads();
    }
  }
}

// ---------------- launch ----------------
extern "C" void kernel_launch(void* const* d_in, const int* in_sizes, int n_in,
                              void* d_out, int out_size, void* d_ws, size_t ws_size,
                              hipStream_t stream) {
  const float* emb = (const float*)d_in[0];
  const float* enc = (const float*)d_in[1];
  const int*   cap = (const int*)d_in[2];
  const float* Wih = (const float*)d_in[3];
  const float* Whh = (const float*)d_in[4];
  const float* bih = (const float*)d_in[5];
  const float* bhh = (const float*)d_in[6];
  const float* Wh0 = (const float*)d_in[7];
  const float* bh0 = (const float*)d_in[8];
  const float* Wc0 = (const float*)d_in[9];
  const float* bc0 = (const float*)d_in[10];
  const float* Wfc = (const float*)d_in[11];
  const float* bfc = (const float*)d_in[12];
  float* out = (float*)d_out;

  char* ws = (char*)d_ws;
  size_t o = 0;
  auto carve = [&](size_t bytes) { void* p = ws + o; o += (bytes + 255) & ~(size_t)255; return p; };
  unsigned short* WihB = (unsigned short*)carve((size_t)G4_ * E_ * 2);   // 2 MB
  unsigned short* WhhB = (unsigned short*)carve((size_t)G4_ * H_ * 2);   // 2 MB
  unsigned short* WfcB = (unsigned short*)carve((size_t)V_ * H_ * 2);    // 32.8 MB
  unsigned short* AxB  = (unsigned short*)carve((size_t)MPAD_ * E_ * 2); // 3.3 MB
  float*          Gx   = (float*)carve((size_t)MPAD_ * G4_ * 4);         // 26.2 MB
  unsigned short* Hall = (unsigned short*)carve((size_t)MPAD_ * H_ * 2); // 3.3 MB
  unsigned short* hb0  = (unsigned short*)carve((size_t)B_ * H_ * 2);
  unsigned short* hb1  = (unsigned short*)carve((size_t)B_ * H_ * 2);
  float*          cst  = (float*)carve((size_t)B_ * H_ * 4);
  int*            bar  = (int*)carve(256);
  (void)ws_size; (void)in_sizes; (void)n_in; (void)out_size;

  hipMemsetAsync(bar, 0, sizeof(int), stream);
  convert_kernel<<<dim3(2048), dim3(256), 0, stream>>>(Wih, Whh, Wfc, emb, WihB, WhhB, WfcB, AxB);
  init_kernel<<<dim3(64, 4), dim3(256), 0, stream>>>(enc, cap, Wh0, bh0, Wc0, bc0, hb0, cst,
                                                     out + (size_t)B_ * T_ * V_);
  gemm_bf16<false><<<dim3(G4_ / 128, MPAD_ / 128), dim3(256), 0, stream>>>(
      AxB, WihB, Gx, bih, bhh, nullptr, G4_, nullptr);
  lstm_persist<<<dim3(NWG_REC), dim3(256), 0, stream>>>(Gx, WhhB, hb0, hb1, cst, Hall, cap, bar);
  gemm_bf16<true><<<dim3(6250), dim3(256), 0, stream>>>(
      Hall, WfcB, nullptr, bfc, nullptr, cap, V_, out);
}

// Round 3
// 588.085 us; speedup vs baseline: 1.7821x; 1.1792x over previous
//
#include <hip/hip_runtime.h>
#include <stdint.h>

#define B_    64
#define T_    49
#define E_    512
#define H_    512
#define ENC_  1024
#define V_    32000
#define G4_   2048        // 4*H
#define M_    3136        // T_*B_
#define MPAD_ 3200        // padded to 25*128
#define NPROD 32
#define NWG   512
#define NTILES 6250       // 25 mt * 250 nt

typedef __attribute__((ext_vector_type(8))) short bf16x8;
typedef __attribute__((ext_vector_type(4))) float f32x4;

static __device__ __forceinline__ unsigned short f2bf(float f) {
  union { float f; uint32_t u; } v; v.f = f;
  uint32_t r = v.u + 0x7FFFu + ((v.u >> 16) & 1u);
  return (unsigned short)(r >> 16);
}

static __device__ __forceinline__ void async16(const void* g, void* lds) {
  __builtin_amdgcn_global_load_lds(
      (const __attribute__((address_space(1))) unsigned int*)g,
      (__attribute__((address_space(3))) unsigned int*)lds, 16, 0, 0);
}

static __device__ __forceinline__ float sigf(float x) { return 1.0f / (1.0f + expf(-x)); }

// ---------------- convert weights to bf16 (+ embeddings transpose (b,t)->(t,b)) ----------------
__global__ __launch_bounds__(256) void convert_kernel(
    const float* __restrict__ Wih, const float* __restrict__ Whh,
    const float* __restrict__ Wfc, const float* __restrict__ emb,
    unsigned short* __restrict__ WihB, unsigned short* __restrict__ WhhB,
    unsigned short* __restrict__ WfcB, unsigned short* __restrict__ AxB) {
  const int n_wih = (G4_ * E_) / 4;
  const int n_whh = (G4_ * H_) / 4;
  const int n_wfc = (V_ * H_) / 4;
  const int n_emb = (B_ * T_ * E_) / 4;
  const int n_pad = ((MPAD_ - M_) * E_) / 4;
  const long total = (long)n_wih + n_whh + n_wfc + n_emb + n_pad;
  for (long u = (long)blockIdx.x * blockDim.x + threadIdx.x; u < total;
       u += (long)gridDim.x * blockDim.x) {
    long i = u;
    if (i < n_wih) {
      float4 v = ((const float4*)Wih)[i];
      ushort4 o; o.x = f2bf(v.x); o.y = f2bf(v.y); o.z = f2bf(v.z); o.w = f2bf(v.w);
      ((ushort4*)WihB)[i] = o; continue;
    }
    i -= n_wih;
    if (i < n_whh) {
      float4 v = ((const float4*)Whh)[i];
      ushort4 o; o.x = f2bf(v.x); o.y = f2bf(v.y); o.z = f2bf(v.z); o.w = f2bf(v.w);
      ((ushort4*)WhhB)[i] = o; continue;
    }
    i -= n_whh;
    if (i < n_wfc) {
      float4 v = ((const float4*)Wfc)[i];
      ushort4 o; o.x = f2bf(v.x); o.y = f2bf(v.y); o.z = f2bf(v.z); o.w = f2bf(v.w);
      ((ushort4*)WfcB)[i] = o; continue;
    }
    i -= n_wfc;
    if (i < n_emb) {
      int bt = (int)(i >> 7);
      int e4 = (int)(i & 127);
      int b = bt / T_, t = bt - b * T_;
      float4 v = ((const float4*)emb)[i];
      ushort4 o; o.x = f2bf(v.x); o.y = f2bf(v.y); o.z = f2bf(v.z); o.w = f2bf(v.w);
      ((ushort4*)AxB)[((long)(t * 64 + b) << 7) + e4] = o; continue;
    }
    i -= n_emb;
    ushort4 z; z.x = z.y = z.z = z.w = 0;
    ((ushort4*)AxB)[((long)M_ << 7) + i] = z;
  }
}

// ---------------- init: h0, c0 (fp32) + decode_lengths to out tail ----------------
__global__ __launch_bounds__(256) void init_kernel(
    const float* __restrict__ enc, const int* __restrict__ cap,
    const float* __restrict__ Wh, const float* __restrict__ bh,
    const float* __restrict__ Wc, const float* __restrict__ bc,
    unsigned short* __restrict__ h0b, float* __restrict__ c0,
    float* __restrict__ out_dl) {
  __shared__ __align__(16) float e[ENC_];
  const int b = blockIdx.x, q = blockIdx.y, tid = threadIdx.x;
  ((float4*)e)[tid] = ((const float4*)(enc + (size_t)b * ENC_))[tid];
  __syncthreads();
  const bool is_c = tid >= 128;
  const int j = q * 128 + (tid & 127);
  const float* W = is_c ? Wc : Wh;
  float s = is_c ? bc[j] : bh[j];
  const float4* wr = (const float4*)(W + (size_t)j * ENC_);
  const float4* e4 = (const float4*)e;
#pragma unroll 4
  for (int k = 0; k < ENC_ / 4; ++k) {
    float4 w = wr[k], v = e4[k];
    s += w.x * v.x + w.y * v.y + w.z * v.z + w.w * v.w;
  }
  if (is_c) c0[(size_t)b * H_ + j] = s;
  else      h0b[(size_t)b * H_ + j] = f2bf(s);
  if (b == 0 && q == 0 && tid < B_) out_dl[tid] = (float)(cap[tid] - 1);
}

// ---------------- Gx GEMM: Gx = AxB @ WihB^T + bih + bhh (128x128 tile, K=512) ----------------
__global__ __launch_bounds__(256) void gemm_gx(
    const unsigned short* __restrict__ A, const unsigned short* __restrict__ Bm,
    float* __restrict__ C, const float* __restrict__ bias0, const float* __restrict__ bias1) {
  __shared__ __align__(16) char smem[65536];
  const int tid = threadIdx.x, lane = tid & 63, wid = tid >> 6;
  const int nt = blockIdx.x, mt = blockIdx.y;
  const int wr = wid >> 1, wc = wid & 1;
  const int m0 = mt * 128, n0 = nt * 128;
  f32x4 acc[4][4] = {};

  auto stage = [&](int buf, int kit) {
    const int k0b = kit * 128;
#pragma unroll
    for (int i = 0; i < 4; ++i) {
      int chunk = wid * 4 + i;
      int d = chunk * 1024 + lane * 16;
      int row = d >> 7, colb = d & 127;
      int sc = colb ^ ((row & 7) << 4);
      async16((const char*)A + (size_t)(m0 + row) * 1024 + k0b + sc,
              smem + buf * 16384 + chunk * 1024);
      async16((const char*)Bm + (size_t)(n0 + row) * 1024 + k0b + sc,
              smem + 32768 + buf * 16384 + chunk * 1024);
    }
  };

  stage(0, 0);
  __syncthreads();
  for (int kit = 0; kit < 8; ++kit) {
    const int buf = kit & 1;
    if (kit < 7) stage(buf ^ 1, kit + 1);
    const char* Ab = smem + buf * 16384;
    const char* Bb = smem + 32768 + buf * 16384;
#pragma unroll
    for (int kb = 0; kb < 2; ++kb) {
      const int colb = kb * 64 + (lane >> 4) * 16;
      bf16x8 af[4], bfb[4];
#pragma unroll
      for (int rt = 0; rt < 4; ++rt) {
        int ar = wr * 64 + rt * 16 + (lane & 15);
        af[rt] = *(const bf16x8*)(Ab + ar * 128 + (colb ^ ((ar & 7) << 4)));
        int br = wc * 64 + rt * 16 + (lane & 15);
        bfb[rt] = *(const bf16x8*)(Bb + br * 128 + (colb ^ ((br & 7) << 4)));
      }
#pragma unroll
      for (int i = 0; i < 4; ++i)
#pragma unroll
        for (int j = 0; j < 4; ++j)
          acc[i][j] = __builtin_amdgcn_mfma_f32_16x16x32_bf16(af[i], bfb[j], acc[i][j], 0, 0, 0);
    }
    __syncthreads();
  }
#pragma unroll
  for (int i = 0; i < 4; ++i) {
    const int rbase = m0 + wr * 64 + i * 16 + (lane >> 4) * 4;
#pragma unroll
    for (int j = 0; j < 4; ++j) {
      const int col = n0 + wc * 64 + j * 16 + (lane & 15);
#pragma unroll
      for (int r = 0; r < 4; ++r)
        C[(size_t)(rbase + r) * G4_ + col] = acc[i][j][r] + bias0[col] + bias1[col];
    }
  }
}

// ---------------- fused: persistent LSTM producers (blocks 0..31) + vocab-GEMM consumers ----------------
// ctrl[w*16] = flag of producer w (monotonic); ctrl[512] = prog (timesteps complete);
// ctrl[528] = tile counter. All zeroed per call by hipMemsetAsync.
__global__ __launch_bounds__(256) void fused_kernel(
    const float* __restrict__ Gx, const unsigned short* __restrict__ WhhB,
    const unsigned short* __restrict__ h0b, const float* __restrict__ c0,
    unsigned short* __restrict__ hsl, unsigned short* __restrict__ Hall,
    const unsigned short* __restrict__ WfcB, const float* __restrict__ bfc,
    const int* __restrict__ cap, float* __restrict__ outp,
    int* __restrict__ ctrl) {
  __shared__ __align__(16) char smem[81920];
  const int tid = threadIdx.x, lane = tid & 63, g = tid >> 6;

  if (blockIdx.x < NPROD) {
    // ================= producer: one WG = 16 h-cols, all 49 steps =================
    __builtin_amdgcn_s_setprio(1);
    const int w = blockIdx.x, hc0 = w * 16;
    // loop-invariant Whh B-fragments in registers (64 VGPRs, reused 49x)
    const int gcol = g * 512 + hc0 + (lane & 15);
    const int ko = (lane >> 4) * 8;
    bf16x8 wf[16];
#pragma unroll
    for (int kb = 0; kb < 16; ++kb)
      wf[kb] = *(const bf16x8*)&WhhB[(size_t)gcol * 512 + kb * 32 + ko];
    const int b = tid >> 2, hq = (tid & 3) * 4, hc = hc0 + hq;
    const int dl = cap[b] - 1;
    f32x4 creg = *(const f32x4*)&c0[b * H_ + hc];
    ushort4 hold = *(const ushort4*)&h0b[b * H_ + hc];
    // swizzled in-slice byte offset for this thread's ushort4 (cols hq..hq+3 of batch b)
    const int myoff = ((b * 32) ^ (((b >> 2) & 7) << 4) ^ ((hq >> 3) << 4)) + ((hq & 7) * 2);
    // write initial slice h(0) into buf0
    *(ushort4*)((char*)hsl + w * 2048 + myoff) = hold;
    // per-row-tile swizzled A-read bases
    int arb[4];
#pragma unroll
    for (int rt = 0; rt < 4; ++rt) {
      int ar = rt * 16 + (lane & 15);
      arb[rt] = (ar * 32) ^ (((ar >> 2) & 7) << 4) ^ (((lane >> 4) & 1) << 4);
    }
    const int chunk_hi = lane >> 5;
    float (*gl)[64][16] = (float (*)[64][16])(smem + 65536);
    __syncthreads();
    if (tid == 0)
      __hip_atomic_store(&ctrl[w * 16], 1, __ATOMIC_RELEASE, __HIP_MEMORY_SCOPE_AGENT);

    for (int t = 0; t < T_; ++t) {
      // prefetch Gx(t) (independent of the barrier)
      const size_t gxr = ((size_t)t * 64 + b) * (size_t)G4_ + hc;
      f32x4 xi = *(const f32x4*)&Gx[gxr + 0];
      f32x4 xf = *(const f32x4*)&Gx[gxr + 512];
      f32x4 xg = *(const f32x4*)&Gx[gxr + 1024];
      f32x4 xo = *(const f32x4*)&Gx[gxr + 1536];
      __builtin_amdgcn_sched_barrier(0);
      // wait until all 32 slices of h(t) are published (flag >= t+1)
      if (tid < 64) {
        const int need = t + 1;
        for (;;) {
          int v = (lane < NPROD)
                      ? __hip_atomic_load(&ctrl[lane * 16], __ATOMIC_RELAXED, __HIP_MEMORY_SCOPE_AGENT)
                      : need;
          if (__all(v >= need)) break;
          __builtin_amdgcn_s_sleep(1);
        }
        if (tid == 0) {
          __builtin_amdgcn_fence(__ATOMIC_ACQUIRE, "agent");
          if (w == 0 && t > 0)
            __hip_atomic_store(&ctrl[512], t, __ATOMIC_RELEASE, __HIP_MEMORY_SCOPE_AGENT);
        }
      }
      __syncthreads();
      // stage all 32 slices (64KB, linear copy; swizzle baked into slice data)
      {
        const char* src = (const char*)hsl + (t & 1) * 65536;
#pragma unroll
        for (int it = 0; it < 16; ++it) {
          const int chunk = g * 16 + it;
          async16(src + chunk * 1024 + lane * 16, smem + chunk * 1024);
        }
      }
      __syncthreads();
      // gates(g-block) = h(t) @ Whh^T
      f32x4 acc[4] = {};
#pragma unroll
      for (int kb = 0; kb < 16; ++kb) {
        const int cbase = (kb * 2 + chunk_hi) * 2048;
#pragma unroll
        for (int rt = 0; rt < 4; ++rt) {
          bf16x8 af = *(const bf16x8*)(smem + cbase + arb[rt]);
          acc[rt] = __builtin_amdgcn_mfma_f32_16x16x32_bf16(af, wf[kb], acc[rt], 0, 0, 0);
        }
      }
#pragma unroll
      for (int rt = 0; rt < 4; ++rt)
#pragma unroll
        for (int r = 0; r < 4; ++r)
          gl[g][rt * 16 + (lane >> 4) * 4 + r][lane & 15] = acc[rt][r];
      __syncthreads();
      // elementwise LSTM cell
      f32x4 vi = xi + *(const f32x4*)&gl[0][b][hq];
      f32x4 vf = xf + *(const f32x4*)&gl[1][b][hq];
      f32x4 vg = xg + *(const f32x4*)&gl[2][b][hq];
      f32x4 vo = xo + *(const f32x4*)&gl[3][b][hq];
      f32x4 cn;
      ushort4 hb16;
      {
        float hv[4];
#pragma unroll
        for (int k = 0; k < 4; ++k) {
          float iv = sigf(vi[k]), fv = sigf(vf[k]), gv = tanhf(vg[k]), ov = sigf(vo[k]);
          cn[k] = fv * creg[k] + iv * gv;
          hv[k] = ov * tanhf(cn[k]);
        }
        hb16.x = f2bf(hv[0]); hb16.y = f2bf(hv[1]); hb16.z = f2bf(hv[2]); hb16.w = f2bf(hv[3]);
      }
      *(ushort4*)&Hall[((size_t)t * 64 + b) * H_ + hc] = hb16;  // pre-mask h_new for preds
      if (t < dl) { hold = hb16; creg = cn; }
      if (t + 1 < T_)
        *(ushort4*)((char*)hsl + ((t + 1) & 1) * 65536 + w * 2048 + myoff) = hold;
      __syncthreads();  // drains this WG's global stores (vmcnt) before flagging
      if (tid == 0)
        __hip_atomic_store(&ctrl[w * 16], t + 2, __ATOMIC_RELEASE, __HIP_MEMORY_SCOPE_AGENT);
    }
    // WG0 publishes final prog = T_
    if (w == 0 && tid < 64) {
      const int need = T_ + 1;
      for (;;) {
        int v = (lane < NPROD)
                    ? __hip_atomic_load(&ctrl[lane * 16], __ATOMIC_RELAXED, __HIP_MEMORY_SCOPE_AGENT)
                    : need;
        if (__all(v >= need)) break;
        __builtin_amdgcn_s_sleep(1);
      }
      if (tid == 0) {
        __builtin_amdgcn_fence(__ATOMIC_ACQUIRE, "agent");
        __hip_atomic_store(&ctrl[512], T_, __ATOMIC_RELEASE, __HIP_MEMORY_SCOPE_AGENT);
      }
    }
    __builtin_amdgcn_s_setprio(0);
  }

  // ================= consumer: vocab GEMM tiles, dependency-gated =================
  int* s_tile = (int*)(smem + 81904);
  const int wid = tid >> 6;
  const int wr = wid >> 1, wc = wid & 1;
  for (;;) {
    __syncthreads();
    if (tid == 0)
      *s_tile = __hip_atomic_fetch_add(&ctrl[528], 1, __ATOMIC_RELAXED, __HIP_MEMORY_SCOPE_AGENT);
    __syncthreads();
    const int tile = *s_tile;
    if (tile >= NTILES) break;
    const int mt = tile / 250, nt = tile % 250;
    const int m0 = mt * 128, n0 = nt * 128;
    const int need = (2 * mt + 2 < T_) ? (2 * mt + 2) : T_;
    if (tid == 0) {
      while (__hip_atomic_load(&ctrl[512], __ATOMIC_RELAXED, __HIP_MEMORY_SCOPE_AGENT) < need)
        __builtin_amdgcn_s_sleep(8);
      __builtin_amdgcn_fence(__ATOMIC_ACQUIRE, "agent");
    }
    __syncthreads();

    f32x4 acc[4][4] = {};
    auto stage = [&](int buf, int kit) {
      const int k0b = kit * 128;
#pragma unroll
      for (int i = 0; i < 4; ++i) {
        int chunk = wid * 4 + i;
        int d = chunk * 1024 + lane * 16;
        int row = d >> 7, colb = d & 127;
        int sc = colb ^ ((row & 7) << 4);
        async16((const char*)Hall + (size_t)(m0 + row) * 1024 + k0b + sc,
                smem + buf * 16384 + chunk * 1024);
        async16((const char*)WfcB + (size_t)(n0 + row) * 1024 + k0b + sc,
                smem + 32768 + buf * 16384 + chunk * 1024);
      }
    };
    stage(0, 0);
    __syncthreads();
    for (int kit = 0; kit < 8; ++kit) {
      const int buf = kit & 1;
      if (kit < 7) stage(buf ^ 1, kit + 1);
      const char* Ab = smem + buf * 16384;
      const char* Bb = smem + 32768 + buf * 16384;
#pragma unroll
      for (int kb = 0; kb < 2; ++kb) {
        const int colb = kb * 64 + (lane >> 4) * 16;
        bf16x8 af[4], bfb[4];
#pragma unroll
        for (int rt = 0; rt < 4; ++rt) {
          int ar = wr * 64 + rt * 16 + (lane & 15);
          af[rt] = *(const bf16x8*)(Ab + ar * 128 + (colb ^ ((ar & 7) << 4)));
          int br = wc * 64 + rt * 16 + (lane & 15);
          bfb[rt] = *(const bf16x8*)(Bb + br * 128 + (colb ^ ((br & 7) << 4)));
        }
#pragma unroll
        for (int i = 0; i < 4; ++i)
#pragma unroll
          for (int j = 0; j < 4; ++j)
            acc[i][j] = __builtin_amdgcn_mfma_f32_16x16x32_bf16(af[i], bfb[j], acc[i][j], 0, 0, 0);
      }
      __syncthreads();
    }
    // epilogue: transpose through LDS (swizzled), coalesced masked float4 stores
    float* Ct = (float*)smem;
#pragma unroll
    for (int j = 0; j < 4; ++j) {
      const int colL = wc * 64 + j * 16 + (lane & 15);
      const float bz = bfc[n0 + colL];
#pragma unroll
      for (int i = 0; i < 4; ++i) {
        const int rb = wr * 64 + i * 16 + (lane >> 4) * 4;
#pragma unroll
        for (int r = 0; r < 4; ++r) {
          const int row = rb + r;
          Ct[row * 128 + (colL ^ ((row & 7) << 2))] = acc[i][j][r] + bz;
        }
      }
    }
    __syncthreads();
    const int c4 = tid & 31;
    const int rsub = tid >> 5;
#pragma unroll
    for (int itr = 0; itr < 16; ++itr) {
      const int row = itr * 8 + rsub;
      const int grow = m0 + row;
      if (grow >= M_) continue;
      const int tt = grow >> 6, bb = grow & 63;
      f32x4 v = {0.0f, 0.0f, 0.0f, 0.0f};
      if (tt < cap[bb] - 1)
        v = *(const f32x4*)&Ct[row * 128 + ((c4 ^ (row & 7)) << 2)];
      *(f32x4*)(outp + ((size_t)bb * T_ + tt) * V_ + n0 + (c4 << 2)) = v;
    }
  }
}

// ---------------- launch ----------------
extern "C" void kernel_launch(void* const* d_in, const int* in_sizes, int n_in,
                              void* d_out, int out_size, void* d_ws, size_t ws_size,
                              hipStream_t stream) {
  const float* emb = (const float*)d_in[0];
  const float* enc = (const float*)d_in[1];
  const int*   cap = (const int*)d_in[2];
  const float* Wih = (const float*)d_in[3];
  const float* Whh = (const float*)d_in[4];
  const float* bih = (const float*)d_in[5];
  const float* bhh = (const float*)d_in[6];
  const float* Wh0 = (const float*)d_in[7];
  const float* bh0 = (const float*)d_in[8];
  const float* Wc0 = (const float*)d_in[9];
  const float* bc0 = (const float*)d_in[10];
  const float* Wfc = (const float*)d_in[11];
  const float* bfc = (const float*)d_in[12];
  float* out = (float*)d_out;

  char* ws = (char*)d_ws;
  size_t o = 0;
  auto carve = [&](size_t bytes) { void* p = ws + o; o += (bytes + 255) & ~(size_t)255; return p; };
  unsigned short* WihB = (unsigned short*)carve((size_t)G4_ * E_ * 2);
  unsigned short* WhhB = (unsigned short*)carve((size_t)G4_ * H_ * 2);
  unsigned short* WfcB = (unsigned short*)carve((size_t)V_ * H_ * 2);
  unsigned short* AxB  = (unsigned short*)carve((size_t)MPAD_ * E_ * 2);
  float*          Gx   = (float*)carve((size_t)MPAD_ * G4_ * 4);
  unsigned short* Hall = (unsigned short*)carve((size_t)MPAD_ * H_ * 2);
  unsigned short* h0b  = (unsigned short*)carve((size_t)B_ * H_ * 2);
  float*          cst  = (float*)carve((size_t)B_ * H_ * 4);
  unsigned short* hsl  = (unsigned short*)carve((size_t)2 * NPROD * 2048);
  int*            ctrl = (int*)carve(4096);
  (void)ws_size; (void)in_sizes; (void)n_in; (void)out_size;

  hipMemsetAsync(ctrl, 0, 4096, stream);
  convert_kernel<<<dim3(2048), dim3(256), 0, stream>>>(Wih, Whh, Wfc, emb, WihB, WhhB, WfcB, AxB);
  init_kernel<<<dim3(64, 4), dim3(256), 0, stream>>>(enc, cap, Wh0, bh0, Wc0, bc0, h0b, cst,
                                                     out + (size_t)B_ * T_ * V_);
  gemm_gx<<<dim3(G4_ / 128, MPAD_ / 128), dim3(256), 0, stream>>>(AxB, WihB, Gx, bih, bhh);
  fused_kernel<<<dim3(NWG), dim3(256), 0, stream>>>(Gx, WhhB, h0b, cst, hsl, Hall,
                                                    WfcB, bfc, cap, out, ctrl);
}